// Round 1
// baseline (484.575 us; speedup 1.0000x reference)
//
#include <hip/hip_runtime.h>
#include <math.h>

#define HIDDEN 1024
#define HEADS 8
#define HEAD 128
#define BATCH 512
#define RSQRT_D 0.08838834764831845f   // 1/sqrt(128)

// ---------------------------------------------------------------------------
// Kernel 1: gate pre-activations + gate math. One block per batch row.
// igate/fgate = qkv(3072) . W[h] + b[h] for 8 heads; then log-sigmoid /
// max-state update. Writes i_gate, f_gate, exp(-max_new) to ws, max_new to out.
// ---------------------------------------------------------------------------
__global__ __launch_bounds__(256) void gates_kernel(
    const float* __restrict__ q, const float* __restrict__ k,
    const float* __restrict__ v, const float* __restrict__ max_state,
    const float* __restrict__ Wi, const float* __restrict__ bi,
    const float* __restrict__ Wf, const float* __restrict__ bf,
    float* __restrict__ ig_out, float* __restrict__ fg_out,
    float* __restrict__ expnm_out, float* __restrict__ maxnew_out)
{
    const int b = blockIdx.x;
    const int t = threadIdx.x;

    float acc_i[HEADS], acc_f[HEADS];
    #pragma unroll
    for (int h = 0; h < HEADS; ++h) { acc_i[h] = 0.f; acc_f[h] = 0.f; }

    const float* qr = q + b * HIDDEN;
    const float* kr = k + b * HIDDEN;
    const float* vr = v + b * HIDDEN;

    // j = t, t+256, ... over 3072 concat(q,k,v) elements
    for (int j = t; j < 3 * HIDDEN; j += 256) {
        float x = (j < HIDDEN) ? qr[j]
                : (j < 2 * HIDDEN) ? kr[j - HIDDEN]
                : vr[j - 2 * HIDDEN];
        #pragma unroll
        for (int h = 0; h < HEADS; ++h) {
            acc_i[h] = fmaf(x, Wi[h * 3 * HIDDEN + j], acc_i[h]);
            acc_f[h] = fmaf(x, Wf[h * 3 * HIDDEN + j], acc_f[h]);
        }
    }

    // wave(64)-level reduce
    #pragma unroll
    for (int h = 0; h < HEADS; ++h) {
        #pragma unroll
        for (int off = 32; off > 0; off >>= 1) {
            acc_i[h] += __shfl_down(acc_i[h], off, 64);
            acc_f[h] += __shfl_down(acc_f[h], off, 64);
        }
    }

    __shared__ float part[4][16];
    __shared__ float pre[16];
    const int wave = t >> 6, lane = t & 63;
    if (lane == 0) {
        #pragma unroll
        for (int h = 0; h < HEADS; ++h) {
            part[wave][h]     = acc_i[h];
            part[wave][8 + h] = acc_f[h];
        }
    }
    __syncthreads();
    if (t < 16) pre[t] = part[0][t] + part[1][t] + part[2][t] + part[3][t];
    __syncthreads();

    if (t < HEADS) {
        float igp = pre[t] + bi[t];
        float fgp = pre[8 + t] + bf[t];
        // stable log_sigmoid
        float lf = (fgp >= 0.f) ? -log1pf(expf(-fgp)) : (fgp - log1pf(expf(fgp)));
        float m_old = max_state[b * HEADS + t];
        float m_new = fmaxf(igp, m_old + lf);
        const int idx = b * HEADS + t;
        ig_out[idx]    = expf(igp - m_new);
        fg_out[idx]    = expf(lf + m_old - m_new);
        expnm_out[idx] = expf(-m_new);
        maxnew_out[idx] = m_new;
    }
}

// ---------------------------------------------------------------------------
// Kernel 2: one block per (b,h). Streams the 128x128 cell tile once:
// cell_new = f*c + (i*k̂[d1]) * v[d2]; numerator[d2] = sum_d1 q[d1]*cell_new;
// norm_new, qn_dot, denominator, GroupNorm epilogue all fused.
// Thread layout: tx = t&31 (float4 column group), ty = t>>5 (row group of 16).
// ---------------------------------------------------------------------------
__global__ __launch_bounds__(256) void mlstm_main(
    const float* __restrict__ q, const float* __restrict__ k,
    const float* __restrict__ v,
    const float* __restrict__ cell_state, const float* __restrict__ norm_state,
    const float* __restrict__ gn_gamma, const float* __restrict__ gn_beta,
    const float* __restrict__ ig, const float* __restrict__ fg,
    const float* __restrict__ expnm,
    float* __restrict__ out, float* __restrict__ cell_new,
    float* __restrict__ norm_new)
{
    const int bh = blockIdx.x;
    const int b = bh >> 3, h = bh & 7;
    const int t = threadIdx.x;
    const int tx = t & 31, ty = t >> 5;

    __shared__ __align__(16) float q_s[HEAD];
    __shared__ __align__(16) float ikh_s[HEAD];
    __shared__ float4 red[8][32];
    __shared__ float inv_denom_s;

    const float i_gate = ig[bh];
    const float f_gate = fg[bh];

    const float* qrow = q + b * HIDDEN + h * HEAD;
    const float* krow = k + b * HIDDEN + h * HEAD;
    const float* vrow = v + b * HIDDEN + h * HEAD;

    if (t < HEAD) {
        q_s[t]   = qrow[t];
        ikh_s[t] = i_gate * krow[t] * RSQRT_D;   // i_gate * k_hat[d1]
    }
    __syncthreads();

    const float4* c_in  = (const float4*)(cell_state + (size_t)bh * HEAD * HEAD);
    float4*       c_out = (float4*)(cell_new   + (size_t)bh * HEAD * HEAD);

    const float4 v4 = ((const float4*)vrow)[tx];

    float4 num = make_float4(0.f, 0.f, 0.f, 0.f);

    #pragma unroll
    for (int i = 0; i < 16; ++i) {
        const int d1 = ty + (i << 3);
        float4 c = c_in[d1 * 32 + tx];
        const float a = ikh_s[d1];
        float4 nc;
        nc.x = fmaf(f_gate, c.x, a * v4.x);
        nc.y = fmaf(f_gate, c.y, a * v4.y);
        nc.z = fmaf(f_gate, c.z, a * v4.z);
        nc.w = fmaf(f_gate, c.w, a * v4.w);
        c_out[d1 * 32 + tx] = nc;
        const float qd = q_s[d1];
        num.x = fmaf(qd, nc.x, num.x);
        num.y = fmaf(qd, nc.y, num.y);
        num.z = fmaf(qd, nc.z, num.z);
        num.w = fmaf(qd, nc.w, num.w);
    }

    red[ty][tx] = num;
    __syncthreads();

    // tree-reduce the 8 row-group partials per column group
    #pragma unroll
    for (int s = 4; s > 0; s >>= 1) {
        if (ty < s) {
            float4 o = red[ty + s][tx];
            float4 m = red[ty][tx];
            m.x += o.x; m.y += o.y; m.z += o.z; m.w += o.w;
            red[ty][tx] = m;
        }
        __syncthreads();
    }

    // norm_new + qn_dot + denominator (lanes 0..31 of wave 0)
    if (t < 32) {
        const float4 ns  = ((const float4*)(norm_state + (size_t)bh * HEAD))[t];
        const float4 q4  = ((const float4*)q_s)[t];
        const float4 ik4 = ((const float4*)ikh_s)[t];
        float4 nn;
        nn.x = fmaf(f_gate, ns.x, ik4.x);
        nn.y = fmaf(f_gate, ns.y, ik4.y);
        nn.z = fmaf(f_gate, ns.z, ik4.z);
        nn.w = fmaf(f_gate, ns.w, ik4.w);
        ((float4*)(norm_new + (size_t)bh * HEAD))[t] = nn;

        float qn = q4.x * nn.x + q4.y * nn.y + q4.z * nn.z + q4.w * nn.w;
        #pragma unroll
        for (int off = 16; off > 0; off >>= 1)
            qn += __shfl_down(qn, off, 32);
        if (t == 0) {
            const float denom = fmaxf(fabsf(qn), expnm[bh]) + 1e-6f;
            inv_denom_s = 1.0f / denom;
        }
    }
    __syncthreads();

    // GroupNorm epilogue over the 128 outputs of this (b,h)
    if (t < 32) {
        const float inv_d = inv_denom_s;
        const float4 numv = red[0][t];
        float4 o;
        o.x = numv.x * inv_d;
        o.y = numv.y * inv_d;
        o.z = numv.z * inv_d;
        o.w = numv.w * inv_d;

        float s  = o.x + o.y + o.z + o.w;
        float ss = o.x * o.x + o.y * o.y + o.z * o.z + o.w * o.w;
        #pragma unroll
        for (int off = 16; off > 0; off >>= 1) {
            s  += __shfl_down(s,  off, 32);
            ss += __shfl_down(ss, off, 32);
        }
        s  = __shfl(s,  0, 32);
        ss = __shfl(ss, 0, 32);

        const float mean = s * (1.f / 128.f);
        const float var  = ss * (1.f / 128.f) - mean * mean;
        const float rstd = rsqrtf(var + 1e-5f);

        const float4 g4 = ((const float4*)(gn_gamma + h * HEAD))[t];
        const float4 b4 = ((const float4*)(gn_beta  + h * HEAD))[t];
        float4 res;
        res.x = fmaf((o.x - mean) * rstd, g4.x, b4.x);
        res.y = fmaf((o.y - mean) * rstd, g4.y, b4.y);
        res.z = fmaf((o.z - mean) * rstd, g4.z, b4.z);
        res.w = fmaf((o.w - mean) * rstd, g4.w, b4.w);
        ((float4*)(out + (size_t)bh * HEAD))[t] = res;
    }
}

// ---------------------------------------------------------------------------
extern "C" void kernel_launch(void* const* d_in, const int* in_sizes, int n_in,
                              void* d_out, int out_size, void* d_ws, size_t ws_size,
                              hipStream_t stream)
{
    const float* q          = (const float*)d_in[0];
    const float* k          = (const float*)d_in[1];
    const float* v          = (const float*)d_in[2];
    const float* cell_state = (const float*)d_in[3];
    const float* norm_state = (const float*)d_in[4];
    const float* max_state  = (const float*)d_in[5];
    const float* Wi         = (const float*)d_in[6];
    const float* bi         = (const float*)d_in[7];
    const float* Wf         = (const float*)d_in[8];
    const float* bf         = (const float*)d_in[9];
    const float* gn_gamma   = (const float*)d_in[10];
    const float* gn_beta    = (const float*)d_in[11];

    // outputs concatenated flat in return order: out, cell_new, norm_new, max_new
    float* out      = (float*)d_out;
    float* cell_new = out      + (size_t)BATCH * HIDDEN;
    float* norm_new = cell_new + (size_t)BATCH * HEADS * HEAD * HEAD;
    float* max_new  = norm_new + (size_t)BATCH * HEADS * HEAD;

    // workspace: i_gate, f_gate, exp(-max_new)  (3 * 4096 floats = 48 KB)
    float* ig    = (float*)d_ws;
    float* fg    = ig + BATCH * HEADS;
    float* expnm = fg + BATCH * HEADS;

    gates_kernel<<<BATCH, 256, 0, stream>>>(
        q, k, v, max_state, Wi, bi, Wf, bf, ig, fg, expnm, max_new);

    mlstm_main<<<BATCH * HEADS, 256, 0, stream>>>(
        q, k, v, cell_state, norm_state, gn_gamma, gn_beta,
        ig, fg, expnm, out, cell_new, norm_new);
}